// Round 1
// baseline (33.954 us; speedup 1.0000x reference)
//
#include <hip/hip_runtime.h>

// CubPL2d: persistence landscape top-2 over pairs.
// x: [B=128, C=64, H=64, W=64] f32; birth/death/pair_dim: [B, C, P=128] i32.
// out: [B, C, D=2, K=2, T=32] f32.
//
// One wave64 per (b,c). Lane l owns output slot (d = l>>5, t = l&31).
// Each lane loads 2 pairs (p = lane, lane+64): coalesced index loads,
// gathered x values. pair dims become a 64-bit ballot (bit p = dim of pair p),
// so the broadcast loop needs only 2 shuffles (birth, death) per pair plus a
// scalar bit test. Top-2 running update with 0-init gives exact reference
// semantics (masked entries are 0, tri clamped at 0, duplicates kept).

constexpr int P = 128;
constexpr float T_MIN = 0.03f;
constexpr float T_MAX = 0.34f;

__global__ __launch_bounds__(256) void pl_topk_kernel(
    const float* __restrict__ x,
    const int* __restrict__ birth_idx,
    const int* __restrict__ death_idx,
    const int* __restrict__ pair_dim,
    float* __restrict__ out)
{
    const int lane = threadIdx.x & 63;
    const int wave_in_blk = threadIdx.x >> 6;
    const int wid = blockIdx.x * 4 + wave_in_blk;   // wid = b*C + c, 0..8191

    const int d_lane = lane >> 5;    // homology dim this lane accumulates
    const int t_idx = lane & 31;     // time step this lane accumulates
    const float t = T_MIN + (T_MAX - T_MIN) * (float)t_idx * (1.0f / 31.0f);

    // ---- load this wave's 128 pairs (2 per lane) ----
    const long pbase = (long)wid * P;
    const int bi0 = birth_idx[pbase + lane];
    const int bi1 = birth_idx[pbase + 64 + lane];
    const int di0 = death_idx[pbase + lane];
    const int di1 = death_idx[pbase + 64 + lane];
    const int dm0 = pair_dim[pbase + lane];
    const int dm1 = pair_dim[pbase + 64 + lane];

    const long xbase = (long)wid * 4096;            // H*W = 4096
    const float xb0 = x[xbase + bi0];
    const float xb1 = x[xbase + bi1];
    const float xd0 = x[xbase + di0];
    const float xd1 = x[xbase + di1];

    // bit p of ballot = pair_dim of pair p (0 or 1)
    const unsigned long long bal0 = __ballot(dm0 == 1);
    const unsigned long long bal1 = __ballot(dm1 == 1);

    float m1 = 0.0f, m2 = 0.0f;

    // ---- broadcast loop: pairs 0..63 (slot 0) ----
    #pragma unroll 16
    for (int p = 0; p < 64; ++p) {
        const float bb = __shfl(xb0, p, 64);
        const float dd = __shfl(xd0, p, 64);
        const int dimp = (int)((bal0 >> p) & 1ull);
        float v = fminf(t - bb, dd - t);          // tri before clamp
        v = (dimp == d_lane) ? v : 0.0f;          // dim mask (0 = neutral)
        m2 = fmaxf(m2, fminf(m1, v));             // uses OLD m1
        m1 = fmaxf(m1, v);
    }
    // ---- pairs 64..127 (slot 1) ----
    #pragma unroll 16
    for (int p = 0; p < 64; ++p) {
        const float bb = __shfl(xb1, p, 64);
        const float dd = __shfl(xd1, p, 64);
        const int dimp = (int)((bal1 >> p) & 1ull);
        float v = fminf(t - bb, dd - t);
        v = (dimp == d_lane) ? v : 0.0f;
        m2 = fmaxf(m2, fminf(m1, v));
        m1 = fmaxf(m1, v);
    }

    // ---- write out: per (b,c) layout is [D, K, T] = 128 floats ----
    float* o = out + (long)wid * 128;
    o[d_lane * 64 + t_idx] = m1;        // k = 0 (max)
    o[d_lane * 64 + 32 + t_idx] = m2;   // k = 1 (second max)
}

extern "C" void kernel_launch(void* const* d_in, const int* in_sizes, int n_in,
                              void* d_out, int out_size, void* d_ws, size_t ws_size,
                              hipStream_t stream) {
    const float* x = (const float*)d_in[0];
    const int* birth_idx = (const int*)d_in[1];
    const int* death_idx = (const int*)d_in[2];
    const int* pair_dim = (const int*)d_in[3];
    float* out = (float*)d_out;

    // 8192 (b,c) slices, one wave each, 4 waves per 256-thread block.
    dim3 grid(2048), block(256);
    hipLaunchKernelGGL(pl_topk_kernel, grid, block, 0, stream,
                       x, birth_idx, death_idx, pair_dim, out);
}

// Round 2
// 27.226 us; speedup vs baseline: 1.2471x; 1.2471x over previous
//
#include <hip/hip_runtime.h>

// CubPL2d: persistence landscape top-2 over pairs.
// x: [B=128, C=64, H=64, W=64] f32; birth/death/pair_dim: [B, C, P=128] i32.
// out: [B, C, D=2, K=2, T=32] f32.
//
// One wave64 per (b,c). Lane l owns output slot (d = l>>5, t = l&31).
// R1 change vs R0: replace the __shfl broadcast loop (2 ds_bpermute + ballot
// bit test + cndmask per pair) with a per-wave LDS table pre-masked by dim:
//   tab[wave][d][p] = (birth_p, death_p) if pair_dim_p == d else (1e30, -1e30)
// Sentinel entries give v = min(t-1e30, -1e30-t) ~ -1e30, which is a no-op in
// the 0-initialized top-2 update — the dim mask costs zero inner-loop ops.
// Inner loop: one ds_read_b128 (2 pairs, wave-uniform addr per 32-lane half ->
// broadcast, conflict-free) + 12 VALU per 2 pairs.

constexpr int P = 128;
constexpr float T_MIN = 0.03f;
constexpr float T_MAX = 0.34f;
constexpr float BIG = 1e30f;

__global__ __launch_bounds__(256) void pl_topk_kernel(
    const float* __restrict__ x,
    const int* __restrict__ birth_idx,
    const int* __restrict__ death_idx,
    const int* __restrict__ pair_dim,
    float* __restrict__ out)
{
    // [wave][dim][pair] -> (birth, death); 8 KB per 256-thread block
    __shared__ float2 tab[4][2][P];

    const int lane = threadIdx.x & 63;
    const int w = threadIdx.x >> 6;
    const int wid = blockIdx.x * 4 + w;   // wid = b*C + c, 0..8191

    const int d_lane = lane >> 5;    // homology dim this lane accumulates
    const int t_idx = lane & 31;     // time step this lane accumulates
    const float t = T_MIN + (T_MAX - T_MIN) * (float)t_idx * (1.0f / 31.0f);

    // ---- load this wave's 128 pairs (2 per lane), gather x ----
    const long pbase = (long)wid * P;
    const int bi0 = birth_idx[pbase + lane];
    const int bi1 = birth_idx[pbase + 64 + lane];
    const int di0 = death_idx[pbase + lane];
    const int di1 = death_idx[pbase + 64 + lane];
    const int dm0 = pair_dim[pbase + lane];
    const int dm1 = pair_dim[pbase + 64 + lane];

    const long xbase = (long)wid * 4096;  // H*W
    const float xb0 = x[xbase + bi0];
    const float xb1 = x[xbase + bi1];
    const float xd0 = x[xbase + di0];
    const float xd1 = x[xbase + di1];

    // ---- build dim-pre-masked tables (4 ds_write_b64 per lane) ----
    tab[w][dm0][lane]          = make_float2(xb0, xd0);
    tab[w][1 - dm0][lane]      = make_float2(BIG, -BIG);
    tab[w][dm1][64 + lane]     = make_float2(xb1, xd1);
    tab[w][1 - dm1][64 + lane] = make_float2(BIG, -BIG);

    __syncthreads();

    // ---- top-2 scan: 64 x ds_read_b128 (2 pairs each), broadcast reads ----
    float m1 = 0.0f, m2 = 0.0f;
    const float2* tp = &tab[w][d_lane][0];
    #pragma unroll
    for (int p = 0; p < P; p += 2) {
        const float4 e = *reinterpret_cast<const float4*>(&tp[p]);
        const float v0 = fminf(t - e.x, e.y - t);
        const float v1 = fminf(t - e.z, e.w - t);
        m2 = fmaxf(m2, fminf(m1, v0));   // uses OLD m1
        m1 = fmaxf(m1, v0);
        m2 = fmaxf(m2, fminf(m1, v1));
        m1 = fmaxf(m1, v1);
    }

    // ---- write out: per (b,c) layout is [D, K, T] = 128 floats ----
    float* o = out + (long)wid * 128;
    o[d_lane * 64 + t_idx] = m1;        // k = 0 (max)
    o[d_lane * 64 + 32 + t_idx] = m2;   // k = 1 (second max)
}

extern "C" void kernel_launch(void* const* d_in, const int* in_sizes, int n_in,
                              void* d_out, int out_size, void* d_ws, size_t ws_size,
                              hipStream_t stream) {
    const float* x = (const float*)d_in[0];
    const int* birth_idx = (const int*)d_in[1];
    const int* death_idx = (const int*)d_in[2];
    const int* pair_dim = (const int*)d_in[3];
    float* out = (float*)d_out;

    // 8192 (b,c) slices, one wave each, 4 waves per 256-thread block.
    dim3 grid(2048), block(256);
    hipLaunchKernelGGL(pl_topk_kernel, grid, block, 0, stream,
                       x, birth_idx, death_idx, pair_dim, out);
}

// Round 3
// 26.325 us; speedup vs baseline: 1.2898x; 1.0342x over previous
//
#include <hip/hip_runtime.h>

// CubPL2d: persistence landscape top-2 over pairs.
// x: [B=128, C=64, H=64, W=64] f32; birth/death/pair_dim: [B, C, P=128] i32.
// out: [B, C, D=2, K=2, T=32] f32.
//
// One wave64 per (b,c). Lane l owns output slot (d = l>>5, t = l&31).
// R2 changes vs R1:
//  - COMPACTED per-dim LDS tables: pairs of dim d are written contiguously to
//    tab[w][d][0..n_d), position = ballot-popcount prefix (top-2 is order-
//    independent, so any bijective placement works). Scan length drops from
//    128 fixed to n_d (~64 avg): DS reads and inner VALU are ~halved.
//    One sentinel entry at tab[w][d][n_d] absorbs the odd-tail b128 over-read.
//  - NO __syncthreads: tables are strictly per-wave, so a wave-local
//    s_waitcnt lgkmcnt(0) orders ds_write -> ds_read; removes the 4-wave
//    coupling on the slowest gather chain.
//  - idx loads as int2 (3 x dwordx2 instead of 6 x dword); lane owns pairs
//    2*lane and 2*lane+1.
// Divergent loop exit (half d=0 runs ceil(n0/2) iters, half d=1 ceil(n1/2))
// is handled by exec-masking; inactive lanes issue no LDS reads.

constexpr int P = 128;
constexpr float T_MIN = 0.03f;
constexpr float T_MAX = 0.34f;
constexpr float BIG = 1e30f;

__global__ __launch_bounds__(256) void pl_topk_kernel(
    const float* __restrict__ x,
    const int* __restrict__ birth_idx,
    const int* __restrict__ death_idx,
    const int* __restrict__ pair_dim,
    float* __restrict__ out)
{
    // [wave][dim][entry] -> (birth, death); 130 entries: up to 128 + sentinel,
    // and 16B alignment of each dim table (130*8B = 1040 = 65*16). ~8.3 KB/blk.
    __shared__ float2 tab[4][2][130];

    const int lane = threadIdx.x & 63;
    const int w = threadIdx.x >> 6;
    const int wid = blockIdx.x * 4 + w;   // wid = b*C + c, 0..8191

    const int d_lane = lane >> 5;    // homology dim this lane accumulates
    const int t_idx = lane & 31;     // time step this lane accumulates
    const float t = T_MIN + (T_MAX - T_MIN) * (float)t_idx * (1.0f / 31.0f);

    // ---- load this wave's 128 pairs (2 consecutive per lane), gather x ----
    const long pbase = (long)wid * P;
    const int2 bi = *reinterpret_cast<const int2*>(&birth_idx[pbase + 2 * lane]);
    const int2 di = *reinterpret_cast<const int2*>(&death_idx[pbase + 2 * lane]);
    const int2 dm = *reinterpret_cast<const int2*>(&pair_dim[pbase + 2 * lane]);

    const long xbase = (long)wid * 4096;  // H*W
    const float xb0 = x[xbase + bi.x];
    const float xb1 = x[xbase + bi.y];
    const float xd0 = x[xbase + di.x];
    const float xd1 = x[xbase + di.y];

    // ---- compaction positions via ballot popcount prefix ----
    const unsigned long long below = (lane == 63) ? ~0ull >> 1
                                                  : (1ull << lane) - 1ull;
    const unsigned long long a_d1 = __ballot(dm.x == 1);   // elem A dims
    const unsigned long long b_d1 = __ballot(dm.y == 1);   // elem B dims
    const unsigned long long a_d0 = ~a_d1;
    const unsigned long long b_d0 = ~b_d1;

    const int nA0 = __popcll(a_d0);                 // dim-0 count among A elems
    const int nA1 = 64 - nA0;
    const int n0 = nA0 + __popcll(b_d0);            // total dim-0 pairs
    const int n1 = P - n0;

    const unsigned long long myA = dm.x ? a_d1 : a_d0;
    const int posA = __popcll(myA & below);
    const unsigned long long myB = dm.y ? b_d1 : b_d0;
    const int posB = (dm.y ? nA1 : nA0) + __popcll(myB & below);

    tab[w][dm.x][posA] = make_float2(xb0, xd0);
    tab[w][dm.y][posB] = make_float2(xb1, xd1);
    if (lane == 0) tab[w][0][n0] = make_float2(BIG, -BIG);  // odd-tail sentinel
    if (lane == 1) tab[w][1][n1] = make_float2(BIG, -BIG);

    // wave-local ordering only: this wave's ds_writes before its ds_reads
    asm volatile("s_waitcnt lgkmcnt(0)" ::: "memory");

    // ---- top-2 scan over my dim's compacted list ----
    const int n_mine = d_lane ? n1 : n0;
    float m1 = 0.0f, m2 = 0.0f;
    const float2* tp = &tab[w][d_lane][0];
    #pragma unroll 2
    for (int p = 0; p < n_mine; p += 2) {
        const float4 e = *reinterpret_cast<const float4*>(&tp[p]);
        const float v0 = fminf(t - e.x, e.y - t);
        const float v1 = fminf(t - e.z, e.w - t);   // sentinel if p+1 == n_mine
        m2 = fmaxf(m2, fminf(m1, v0));   // uses OLD m1
        m1 = fmaxf(m1, v0);
        m2 = fmaxf(m2, fminf(m1, v1));
        m1 = fmaxf(m1, v1);
    }

    // ---- write out: per (b,c) layout is [D, K, T] = 128 floats ----
    float* o = out + (long)wid * 128;
    o[d_lane * 64 + t_idx] = m1;        // k = 0 (max)
    o[d_lane * 64 + 32 + t_idx] = m2;   // k = 1 (second max)
}

extern "C" void kernel_launch(void* const* d_in, const int* in_sizes, int n_in,
                              void* d_out, int out_size, void* d_ws, size_t ws_size,
                              hipStream_t stream) {
    const float* x = (const float*)d_in[0];
    const int* birth_idx = (const int*)d_in[1];
    const int* death_idx = (const int*)d_in[2];
    const int* pair_dim = (const int*)d_in[3];
    float* out = (float*)d_out;

    // 8192 (b,c) slices, one wave each, 4 waves per 256-thread block.
    dim3 grid(2048), block(256);
    hipLaunchKernelGGL(pl_topk_kernel, grid, block, 0, stream,
                       x, birth_idx, death_idx, pair_dim, out);
}